// Round 2
// baseline (214.341 us; speedup 1.0000x reference)
//
#include <hip/hip_runtime.h>
#include <hip/hip_bf16.h>
#include <stdint.h>

// CRF entity layer: B=64, T=512, H=768, K=32
// Phases:
//   1) gemm_pot:   pot[b][t][k] = x[b,t,:]·W[:,k] + b[k]        (ws)
//   2) scan_kernel: blocks 0..31  -> logsumexp forward -> logZ[b]
//                   blocks 32..95 -> viterbi max forward -> va[b][t][k], last[b]
//   3) bp_extract: bp[b][t][k] = argmax_j(va[t-1][j]+trans[j][k])   (parallel)
//   4) backtrace:  log-depth composition scan over step maps (id for t>=len),
//                  writes preds; + sequence score; ll[b] = score - logZ.
//
// ws layout (bytes):
//   pot : 0         .. 4194304   (+4096 pad, scans prefetch up to t=527)
//   va  : 4198400   .. 8392704   (+4096 pad, stores overshoot <= t=518)
//   bp  : 8396800   .. 9445376   (u8)
//   logZ: 9445376   (64 f32)
//   last: 9445632   (64 i32)

#define TT 512
#define KK 32
#define HH 768
#define NB 64

#define WS_POT 0
#define WS_VA  4198400
#define WS_BP  8396800
#define WS_LOGZ 9445376
#define WS_LAST 9445632

__device__ __forceinline__ float wmax32(float v) {
#pragma unroll
  for (int m = 16; m >= 1; m >>= 1) v = fmaxf(v, __shfl_xor(v, m, 32));
  return v;
}
__device__ __forceinline__ float wsum32(float v) {
#pragma unroll
  for (int m = 16; m >= 1; m >>= 1) v += __shfl_xor(v, m, 32);
  return v;
}

// ---------------------------------------------------------------- GEMM ------
// grid 512 x 256. Block: 64 rows (b*t), all 32 cols. H chunked by 64.
__global__ __launch_bounds__(256) void gemm_pot(const float* __restrict__ x,
                                                const float* __restrict__ W,
                                                const float* __restrict__ bias,
                                                float* __restrict__ pot) {
  __shared__ float4 xs4[64][16];   // x tile, slot ^= (r>>2)&3
  __shared__ float4 wt4[32][16];   // W^T tile, slot ^= (c>>1)&15
  const int tid = threadIdx.x;
  const int row0 = blockIdx.x * 64;
  const int cg = tid & 15;          // col pair group
  const int rg = tid >> 4;          // row group (4 rows)
  const int c0 = cg * 2;
  float acc[4][2] = {{0.f, 0.f}, {0.f, 0.f}, {0.f, 0.f}, {0.f, 0.f}};

  for (int h0 = 0; h0 < HH; h0 += 64) {
    // stage x: 64 rows x 64 h = 1024 float4
#pragma unroll
    for (int p = 0; p < 4; ++p) {
      const int fi = tid + p * 256;
      const int r = fi >> 4, s = fi & 15;
      const float4 v = *(const float4*)(&x[(size_t)(row0 + r) * HH + h0 + s * 4]);
      xs4[r][s ^ ((r >> 2) & 3)] = v;
    }
    // stage W transposed: wt[c][hh] = W[h0+hh][c]
    {
      const int c = tid & 31;
      const int hb = (tid >> 5) * 8;
      float* wf = (float*)(&wt4[0][0]);
#pragma unroll
      for (int i2 = 0; i2 < 8; ++i2) {
        const int hh = hb + i2;
        const int slot = (hh >> 2) ^ ((c >> 1) & 15);
        wf[c * 64 + slot * 4 + (hh & 3)] = W[(size_t)(h0 + hh) * KK + c];
      }
    }
    __syncthreads();
#pragma unroll
    for (int s = 0; s < 16; ++s) {
      float4 xv[4];
#pragma unroll
      for (int i = 0; i < 4; ++i) xv[i] = xs4[rg * 4 + i][s ^ (rg & 3)];
      const float4 wv0 = wt4[c0][s ^ cg];
      const float4 wv1 = wt4[c0 + 1][s ^ cg];
#pragma unroll
      for (int i = 0; i < 4; ++i) {
        acc[i][0] += xv[i].x * wv0.x + xv[i].y * wv0.y + xv[i].z * wv0.z + xv[i].w * wv0.w;
        acc[i][1] += xv[i].x * wv1.x + xv[i].y * wv1.y + xv[i].z * wv1.z + xv[i].w * wv1.w;
      }
    }
    __syncthreads();
  }
#pragma unroll
  for (int i = 0; i < 4; ++i) {
    const int row = row0 + rg * 4 + i;
    float2 o = make_float2(acc[i][0] + bias[c0], acc[i][1] + bias[c0 + 1]);
    *(float2*)(&pot[(size_t)row * KK + c0]) = o;
  }
}

// ---------------------------------------------------------------- scans -----
// grid 96 x 64.  blocks 0..31: LSE (2 batches per wave). 32..95: viterbi.
__global__ __launch_bounds__(64) void scan_kernel(const float* __restrict__ pot,
                                                  const int* __restrict__ lens,
                                                  const float* __restrict__ trans,
                                                  float* __restrict__ va,
                                                  float* __restrict__ logZ,
                                                  int* __restrict__ last) {
  const int blk = blockIdx.x;
  const int lane = threadIdx.x;

  if (blk < 32) {
    // ---------------- logsumexp forward ----------------
    __shared__ __align__(16) float es[64];
    const int h = lane >> 5, k = lane & 31;
    const int bb = blk * 2 + h;
    const int len = lens[bb];
    float etr[32];
#pragma unroll
    for (int j = 0; j < 32; ++j) etr[j] = expf(trans[j * KK + k]);
    const float* pp = pot + (size_t)bb * (TT * KK) + k;
    float alpha = pp[0];
    float M = wmax32(alpha);
    const int maxlen = max(len, __shfl_xor(len, 32));
    float pb[8], pn[8];
#pragma unroll
    for (int i = 0; i < 8; ++i) pb[i] = pp[(size_t)(1 + i) * KK];

    for (int tb = 1; tb <= maxlen - 1; tb += 8) {
#pragma unroll
      for (int i = 0; i < 8; ++i) pn[i] = pp[(size_t)(tb + 8 + i) * KK];
#pragma unroll
      for (int i = 0; i < 8; ++i) {
        const int t = tb + i;
        float d = alpha - M;
        if (__any(d > 8.f) || __all(d < -8.f)) {   // defer-max rescale
          M = wmax32(alpha);
          d = alpha - M;
        }
        const float e = exp2f(d * 1.4426950408889634f);
        es[lane] = e;                               // same-wave LDS, in order
        float dot = 0.f;
#pragma unroll
        for (int j = 0; j < 32; ++j) dot += es[h * 32 + j] * etr[j];
        const float anew = M + 0.69314718055994531f * log2f(dot) + pb[i];
        alpha = (t < len) ? anew : alpha;
      }
#pragma unroll
      for (int i = 0; i < 8; ++i) pb[i] = pn[i];
    }
    const float M2 = wmax32(alpha);
    const float ssum = wsum32(exp2f((alpha - M2) * 1.4426950408889634f));
    if (k == 0) logZ[bb] = M2 + 0.69314718055994531f * log2f(ssum);
  } else {
    // ---------------- viterbi max forward ----------------
    __shared__ __align__(16) float vsa[32];
    const int jh = lane >> 5, k = lane & 31;
    const int b = blk - 32;
    const int len = lens[b];
    float tr[16];
#pragma unroll
    for (int i = 0; i < 16; ++i) tr[i] = trans[(jh * 16 + i) * KK + k];
    const float* pp = pot + (size_t)b * (TT * KK) + k;
    float* vap = va + (size_t)b * (TT * KK) + k;
    float valpha = pp[0];
    if (jh == 0) { vsa[k] = valpha; vap[0] = valpha; }
    float pb[8], pn[8];
#pragma unroll
    for (int i = 0; i < 8; ++i) pb[i] = pp[(size_t)(1 + i) * KK];

    for (int tb = 1; tb <= len - 1; tb += 8) {
#pragma unroll
      for (int i = 0; i < 8; ++i) pn[i] = pp[(size_t)(tb + 8 + i) * KK];
#pragma unroll
      for (int i = 0; i < 8; ++i) {
        const int t = tb + i;
        float m = -3.4e38f;
#pragma unroll
        for (int i2 = 0; i2 < 16; ++i2) m = fmaxf(m, vsa[jh * 16 + i2] + tr[i2]);
        const float vnew = fmaxf(m, __shfl_xor(m, 32)) + pb[i];
        valpha = (t < len) ? vnew : valpha;
        if (jh == 0) { vsa[k] = valpha; vap[(size_t)t * KK] = valpha; }
      }
#pragma unroll
      for (int i = 0; i < 8; ++i) pb[i] = pn[i];
    }
    // argmax over k, first-index tiebreak
    float v = valpha;
    int idx = k;
#pragma unroll
    for (int mm = 16; mm >= 1; mm >>= 1) {
      const float vo = __shfl_xor(v, mm, 32);
      const int io = __shfl_xor(idx, mm, 32);
      if (vo > v || (vo == v && io < idx)) { v = vo; idx = io; }
    }
    if (lane == 0) last[b] = idx;
  }
}

// ----------------------------------------------------------- bp extract -----
// grid 512 x 256: block = (batch, 64-t chunk). bp[b][t][k] from va[t-1].
__global__ __launch_bounds__(256) void bp_extract(const float* __restrict__ va,
                                                  const float* __restrict__ trans,
                                                  unsigned char* __restrict__ bp) {
  const int b = blockIdx.x >> 3;
  const int tbase = (blockIdx.x & 7) * 64;
  const int k = threadIdx.x & 31;
  const int ts = threadIdx.x >> 5;
  float tr[32];
#pragma unroll
  for (int j = 0; j < 32; ++j) tr[j] = trans[j * KK + k];
#pragma unroll
  for (int it = 0; it < 8; ++it) {
    const int t = tbase + it * 8 + ts;
    if (t < 1) continue;
    const float* row = va + ((size_t)b * TT + (t - 1)) * KK;
    float best = row[0] + tr[0];
    int bi = 0;
#pragma unroll
    for (int j = 1; j < 32; ++j) {
      const float s = row[j] + tr[j];
      if (s > best) { best = s; bi = j; }        // strict > keeps lowest index
    }
    bp[((size_t)b * TT + t) * KK + k] = (unsigned char)bi;
  }
}

// ------------------------------------------------------------- backtrace ----
// grid 64 x 256. Per-batch: composition scan over step maps g_t (id for t>=len
// and t=0), then down-sweep to get tags[t] for all t; + sequence score + ll.
__global__ __launch_bounds__(256) void backtrace_kernel(
    const unsigned char* __restrict__ bp, const int* __restrict__ lens,
    const int* __restrict__ last, const float* __restrict__ pot,
    const int* __restrict__ y, const float* __restrict__ trans,
    const float* __restrict__ logZ, float* __restrict__ out) {
  __shared__ unsigned char Ls[32736];   // levels 0..9, level l at 32*(1024-(1024>>l))
  __shared__ unsigned char sA[512], sB[512];
  __shared__ float red[256];
  const int b = blockIdx.x, tid = threadIdx.x;
  const int len = lens[b];

  // level 0: g_t
  for (int i = tid; i < TT * KK; i += 256) {
    const int t = i >> 5, k = i & 31;
    Ls[i] = (t >= 1 && t < len) ? bp[((size_t)b * TT + t) * KK + k] : (unsigned char)k;
  }
  __syncthreads();

  // up-sweep: M_l[i] = M_{l-1}[2i] o M_{l-1}[2i+1]
  int off_prev = 0, cnt = 512;
  for (int l = 1; l <= 9; ++l) {
    const int off = 32 * (1024 - (1024 >> l));
    const int n = cnt >> 1;
    for (int i = tid; i < n * 32; i += 256) {
      const int m = i >> 5, k = i & 31;
      const int inner = Ls[off_prev + (2 * m + 1) * 32 + k];
      Ls[off + i] = Ls[off_prev + (2 * m) * 32 + inner];
    }
    __syncthreads();
    off_prev = off;
    cnt = n;
  }

  if (tid == 0) sA[0] = (unsigned char)last[b];
  __syncthreads();

  // down-sweep: s_{l-1,2i+1}=s_{l,i}; s_{l-1,2i}=M_{l-1,2i+1}(s_{l,i})
  unsigned char* cur = sA;
  unsigned char* nxt = sB;
  int c2 = 1;
  for (int l = 9; l >= 1; --l) {
    const int offm = 32 * (1024 - (1024 >> (l - 1)));
    for (int i = tid; i < c2; i += 256) {
      const unsigned char s = cur[i];
      nxt[2 * i + 1] = s;
      nxt[2 * i] = Ls[offm + (2 * i + 1) * 32 + s];
    }
    __syncthreads();
    unsigned char* tmp = cur; cur = nxt; nxt = tmp;
    c2 <<= 1;
  }

  // preds (float, masked)
  for (int t = tid; t < TT; t += 256)
    out[NB + (size_t)b * TT + t] = (t < len) ? (float)cur[t] : 0.f;

  // sequence score
  float acc = 0.f;
  for (int t = tid; t < TT; t += 256) {
    const int yt = y[b * TT + t];
    if (t < len) acc += pot[((size_t)b * TT + t) * KK + yt];
    if (t < len - 1) acc += trans[yt * KK + y[b * TT + t + 1]];
  }
  red[tid] = acc;
  __syncthreads();
  for (int s = 128; s >= 1; s >>= 1) {
    if (tid < s) red[tid] += red[tid + s];
    __syncthreads();
  }
  if (tid == 0) out[b] = red[0] - logZ[b];
}

// ------------------------------------------------------------------ launch --
extern "C" void kernel_launch(void* const* d_in, const int* in_sizes, int n_in,
                              void* d_out, int out_size, void* d_ws, size_t ws_size,
                              hipStream_t stream) {
  const float* x = (const float*)d_in[0];
  const int* y = (const int*)d_in[1];
  const int* lens = (const int*)d_in[2];
  const float* W = (const float*)d_in[3];
  const float* bias = (const float*)d_in[4];
  const float* trans = (const float*)d_in[5];
  float* out = (float*)d_out;
  char* ws = (char*)d_ws;
  float* pot = (float*)(ws + WS_POT);
  float* va = (float*)(ws + WS_VA);
  unsigned char* bp = (unsigned char*)(ws + WS_BP);
  float* logZ = (float*)(ws + WS_LOGZ);
  int* last = (int*)(ws + WS_LAST);

  gemm_pot<<<512, 256, 0, stream>>>(x, W, bias, pot);
  scan_kernel<<<96, 64, 0, stream>>>(pot, lens, trans, va, logZ, last);
  bp_extract<<<512, 256, 0, stream>>>(va, trans, bp);
  backtrace_kernel<<<64, 256, 0, stream>>>(bp, lens, last, pot, y, trans, logZ, out);
}